// Round 7
// baseline (468.242 us; speedup 1.0000x reference)
//
#include <hip/hip_runtime.h>

#define N_NODES 50000
#define E_EDGES 800000
#define DIN 128
#define DOUT 64
#define NBUK 196            // bucket = row >> 8; 196*256 = 50176 >= N
#define BUKCAP 4608         // fixed bucket capacity (mean ~4082, +8 sigma)
#define CHUNK 2048
#define NBLKA 391           // ceil(E/CHUNK)
#define ASTRIDE 136         // bf16 LDS row stride

typedef short short8 __attribute__((ext_vector_type(8)));
typedef float f32x4 __attribute__((ext_vector_type(4)));

static __device__ __forceinline__ short f2bf(float f)
{
    union { float f; unsigned u; } x{f};
    const unsigned r = x.u + 0x7FFFu + ((x.u >> 16) & 1u);   // RNE
    return (short)(r >> 16);
}

// ---------------- K0: one-time prep — W^T bf16, BN scale/shift --------------
__global__ void k_prep(const float* __restrict__ W, const float* __restrict__ gamma,
                       const float* __restrict__ beta, const float* __restrict__ mean,
                       const float* __restrict__ var,
                       unsigned short* __restrict__ Wt, float* __restrict__ sc,
                       float* __restrict__ sh)
{
    const int idx = blockIdx.x * 256 + threadIdx.x;      // 8192 threads
    const int n = idx >> 7, k = idx & 127;
    Wt[n * DIN + k] = (unsigned short)f2bf(W[k * DOUT + n]);
    if (idx < DIN) {
        const float s = gamma[idx] / sqrtf(var[idx] + 1e-5f);
        sc[idx] = s;
        sh[idx] = beta[idx] - mean[idx] * s;
    }
}

// ---------------- K1: fused L2norm + BN + Linear via bf16 MFMA --------------
__global__ __launch_bounds__(256) void k_x(
    const float* __restrict__ H, const float* __restrict__ sc,
    const float* __restrict__ sh, const unsigned short* __restrict__ Wt,
    const float* __restrict__ bias, float* __restrict__ X)
{
    __shared__ short A_s[64][ASTRIDE];
    __shared__ short B_s[64][ASTRIDE];
    const int t = threadIdx.x;
    const int l = t & 63, wv = t >> 6;
    const int R0 = blockIdx.x * 64;

    {   // stage A: 4 threads per row
        const int rloc = t >> 2, sub = t & 3;
        const int r = R0 + rloc;
        float4 h[8];
        if (r < N_NODES) {
            const float4* hp = (const float4*)(H + (size_t)r * DIN + sub * 32);
#pragma unroll
            for (int i = 0; i < 8; ++i) h[i] = hp[i];
        } else {
#pragma unroll
            for (int i = 0; i < 8; ++i) h[i] = make_float4(0.f, 0.f, 0.f, 0.f);
        }
        float ss = 0.f;
#pragma unroll
        for (int i = 0; i < 8; ++i)
            ss += h[i].x * h[i].x + h[i].y * h[i].y + h[i].z * h[i].z + h[i].w * h[i].w;
        ss += __shfl_xor(ss, 1, 64);
        ss += __shfl_xor(ss, 2, 64);
        const float inv = 1.0f / fmaxf(sqrtf(ss), 1e-12f);

        const float4* scp = (const float4*)(sc + sub * 32);
        const float4* shp = (const float4*)(sh + sub * 32);
#pragma unroll
        for (int i = 0; i < 8; ++i) {
            const float4 s4 = scp[i], b4 = shp[i];
            const float e0 = h[i].x * inv * s4.x + b4.x;
            const float e1 = h[i].y * inv * s4.y + b4.y;
            const float e2 = h[i].z * inv * s4.z + b4.z;
            const float e3 = h[i].w * inv * s4.w + b4.w;
            const unsigned u0 = (unsigned short)f2bf(e0) | ((unsigned)(unsigned short)f2bf(e1) << 16);
            const unsigned u1 = (unsigned short)f2bf(e2) | ((unsigned)(unsigned short)f2bf(e3) << 16);
            *(uint2*)&A_s[rloc][sub * 32 + i * 4] = make_uint2(u0, u1);
        }
    }
    {   // stage B: W^T bf16 -> LDS
        const int n = t >> 2, koff = (t & 3) * 32;
        const uint4* src = (const uint4*)(Wt + n * DIN + koff);
#pragma unroll
        for (int i = 0; i < 4; ++i)
            *(uint4*)&B_s[n][koff + i * 8] = src[i];
    }
    __syncthreads();

    const int ml = l & 15, q = l >> 4;
    f32x4 c0, c1, c2, c3;
    {
        const float b0 = bias[ml],      b1 = bias[16 + ml];
        const float b2 = bias[32 + ml], b3 = bias[48 + ml];
        c0 = f32x4{b0, b0, b0, b0};
        c1 = f32x4{b1, b1, b1, b1};
        c2 = f32x4{b2, b2, b2, b2};
        c3 = f32x4{b3, b3, b3, b3};
    }
#pragma unroll
    for (int k0 = 0; k0 < 4; ++k0) {
        const short8 a  = *(const short8*)&A_s[wv * 16 + ml][k0 * 32 + q * 8];
        const short8 b0 = *(const short8*)&B_s[ml][k0 * 32 + q * 8];
        const short8 b1 = *(const short8*)&B_s[16 + ml][k0 * 32 + q * 8];
        const short8 b2 = *(const short8*)&B_s[32 + ml][k0 * 32 + q * 8];
        const short8 b3 = *(const short8*)&B_s[48 + ml][k0 * 32 + q * 8];
        c0 = __builtin_amdgcn_mfma_f32_16x16x32_bf16(a, b0, c0, 0, 0, 0);
        c1 = __builtin_amdgcn_mfma_f32_16x16x32_bf16(a, b1, c1, 0, 0, 0);
        c2 = __builtin_amdgcn_mfma_f32_16x16x32_bf16(a, b2, c2, 0, 0, 0);
        c3 = __builtin_amdgcn_mfma_f32_16x16x32_bf16(a, b3, c3, 0, 0, 0);
    }
#pragma unroll
    for (int i = 0; i < 4; ++i) {
        const int row = R0 + wv * 16 + q * 4 + i;
        if (row < N_NODES) {
            float* xr = X + (size_t)row * DOUT;
            xr[ml]      = c0[i];
            xr[16 + ml] = c1[i];
            xr[32 + ml] = c2[i];
            xr[48 + ml] = c3[i];
        }
    }
}

// ---------------- K2: pass A — bucket sort into fixed-cap windows -----------
// pack: col(16b) | (row&255)<<16 | (row>>8)<<24
__global__ __launch_bounds__(256) void k_passA(
    const int* __restrict__ rows, const int* __restrict__ cols,
    const float* __restrict__ vals, int* __restrict__ gcursor,
    uint2* __restrict__ mid)
{
    __shared__ int lhist[NBUK], lstart[NBUK], lcur[NBUK], gbase[NBUK];
    __shared__ int scn[256];
    __shared__ uint2 lbin[CHUNK];
    const int t = threadIdx.x;
    const int e0 = blockIdx.x * CHUNK;
    const int nC = min(CHUNK, E_EDGES - e0);

    if (t < NBUK) lhist[t] = 0;
    __syncthreads();

    uint2 pr[8];
#pragma unroll
    for (int k = 0; k < 8; ++k) {
        const int e = e0 + k * 256 + t;
        if (e < E_EDGES) {
            const int r = rows[e];
            pr[k] = make_uint2(__float_as_uint(vals[e]),
                               (unsigned)cols[e] | ((unsigned)(r & 255) << 16)
                                                 | ((unsigned)(r >> 8) << 24));
            atomicAdd(&lhist[r >> 8], 1);
        } else {
            pr[k] = make_uint2(0u, 0xFFFFFFFFu);
        }
    }
    __syncthreads();

    const int v = (t < NBUK) ? lhist[t] : 0;
    scn[t] = v;
    __syncthreads();
    for (int o = 1; o < 256; o <<= 1) {
        const int u = (t >= o) ? scn[t - o] : 0;
        __syncthreads();
        scn[t] += u;
        __syncthreads();
    }
    if (t < NBUK) {
        const int ex = scn[t] - v;
        lstart[t] = ex;
        lcur[t] = ex;
        gbase[t] = t * BUKCAP + (v ? atomicAdd(&gcursor[t], v) : 0);
    }
    __syncthreads();

#pragma unroll
    for (int k = 0; k < 8; ++k) {
        const unsigned pk = pr[k].y;
        if (pk != 0xFFFFFFFFu) {
            const int bk = pk >> 24;
            lbin[atomicAdd(&lcur[bk], 1)] = pr[k];
        }
    }
    __syncthreads();

    for (int i = t; i < nC; i += 256) {
        const uint2 p = lbin[i];
        const int bk = p.y >> 24;
        const int idx = gbase[bk] + (i - lstart[bk]);
        if (idx < (bk + 1) * BUKCAP)              // overflow guard (P ~ 1e-13)
            mid[idx] = p;
    }
}

// ---------------- K3: bucket SpMM + LeakyReLU — 64KB LDS accumulator --------
// One 1024-thread block per bucket (256 rows x 64 cols fp32 in LDS). Edges
// read via wave-uniform scalar loads; per edge: 1 coalesced 256B X-gather +
// 1 ds_add_f32 (2 lanes/bank = conflict-free). Dense coalesced epilogue.
__global__ __launch_bounds__(1024) void k_spmm2(
    const int* __restrict__ gcursor, const uint2* __restrict__ mid,
    const float* __restrict__ X, float* __restrict__ out)
{
    __shared__ float acc[256 * DOUT];
    const int t = threadIdx.x;
    const int b = blockIdx.x;
    const int lane = t & 63;

    float4* accv = (float4*)acc;
#pragma unroll
    for (int k = 0; k < 4; ++k)
        accv[k * 1024 + t] = make_float4(0.f, 0.f, 0.f, 0.f);
    __syncthreads();

    const int total = min(__builtin_amdgcn_readfirstlane(gcursor[b]), BUKCAP);
    const int wv = __builtin_amdgcn_readfirstlane(threadIdx.x >> 6);
    const int L  = (total + 15) >> 4;
    const int cs = wv * L;
    const int ce = min(cs + L, total);
    const uint2* src = mid + (size_t)b * BUKCAP;

    int c = cs;
    for (; c + 3 < ce; c += 4) {
        const uint2 p0 = src[c],     p1 = src[c + 1];
        const uint2 p2 = src[c + 2], p3 = src[c + 3];
        const float x0 = X[(int)(p0.y & 0xFFFFu) * DOUT + lane];
        const float x1 = X[(int)(p1.y & 0xFFFFu) * DOUT + lane];
        const float x2 = X[(int)(p2.y & 0xFFFFu) * DOUT + lane];
        const float x3 = X[(int)(p3.y & 0xFFFFu) * DOUT + lane];
        atomicAdd(&acc[(int)((p0.y >> 16) & 255u) * DOUT + lane], __uint_as_float(p0.x) * x0);
        atomicAdd(&acc[(int)((p1.y >> 16) & 255u) * DOUT + lane], __uint_as_float(p1.x) * x1);
        atomicAdd(&acc[(int)((p2.y >> 16) & 255u) * DOUT + lane], __uint_as_float(p2.x) * x2);
        atomicAdd(&acc[(int)((p3.y >> 16) & 255u) * DOUT + lane], __uint_as_float(p3.x) * x3);
    }
    for (; c < ce; ++c) {
        const uint2 p = src[c];
        const float x = X[(int)(p.y & 0xFFFFu) * DOUT + lane];
        atomicAdd(&acc[(int)((p.y >> 16) & 255u) * DOUT + lane], __uint_as_float(p.x) * x);
    }
    __syncthreads();

    const int r0 = b << 8;
#pragma unroll
    for (int k = 0; k < 4; ++k) {
        const int off = k * 4096 + t * 4;
        if (r0 + (off >> 6) < N_NODES) {
            float4 a = *(float4*)&acc[off];
            a.x = (a.x >= 0.f) ? a.x : 0.01f * a.x;
            a.y = (a.y >= 0.f) ? a.y : 0.01f * a.y;
            a.z = (a.z >= 0.f) ? a.z : 0.01f * a.z;
            a.w = (a.w >= 0.f) ? a.w : 0.01f * a.w;
            *(float4*)(out + (size_t)r0 * DOUT + off) = a;
        }
    }
}

extern "C" void kernel_launch(void* const* d_in, const int* in_sizes, int n_in,
                              void* d_out, int out_size, void* d_ws, size_t ws_size,
                              hipStream_t stream)
{
    const float* H     = (const float*)d_in[0];
    const int*   rows  = (const int*)  d_in[1];
    const int*   cols  = (const int*)  d_in[2];
    const float* vals  = (const float*)d_in[3];
    const float* gamma = (const float*)d_in[4];
    const float* beta  = (const float*)d_in[5];
    const float* mean  = (const float*)d_in[6];
    const float* var   = (const float*)d_in[7];
    const float* W     = (const float*)d_in[8];
    const float* bias  = (const float*)d_in[9];
    float* out = (float*)d_out;

    char* ws = (char*)d_ws;
    float*          X       = (float*)(ws);                     // 12,800,000 B
    int*            gcursor = (int*)  (ws + 12800000);          //        784 B
    uint2*          mid     = (uint2*)(ws + 12800800);          //  7,225,344 B
    unsigned short* Wt      = (unsigned short*)(ws + 20026144); //     16,384 B
    float*          sc      = (float*)(ws + 20042528);          //        512 B
    float*          sh      = (float*)(ws + 20043040);          //        512 B

    hipMemsetAsync(gcursor, 0, NBUK * sizeof(int), stream);

    k_prep<<<32, 256, 0, stream>>>(W, gamma, beta, mean, var, Wt, sc, sh);
    k_x<<<(N_NODES + 63) / 64, 256, 0, stream>>>(H, sc, sh, Wt, bias, X);
    k_passA<<<NBLKA, 256, 0, stream>>>(rows, cols, vals, gcursor, mid);
    k_spmm2<<<NBUK, 1024, 0, stream>>>(gcursor, mid, X, out);
}

// Round 8
// 159.876 us; speedup vs baseline: 2.9288x; 2.9288x over previous
//
#include <hip/hip_runtime.h>
#include <hip/hip_fp16.h>

#define N_NODES 50000
#define E_EDGES 800000
#define DIN 128
#define DOUT 64
#define NBUK 196            // bucket = row >> 8
#define BUKCAP 4608         // fixed window capacity (mean ~4082, +8 sigma)
#define CHUNK 2048
#define NBLKA 391           // ceil(E/CHUNK)
#define ASTRIDE 136         // bf16 LDS row stride

typedef short short8 __attribute__((ext_vector_type(8)));
typedef float f32x4 __attribute__((ext_vector_type(4)));

static __device__ __forceinline__ short f2bf(float f)
{
    union { float f; unsigned u; } x{f};
    const unsigned r = x.u + 0x7FFFu + ((x.u >> 16) & 1u);   // RNE
    return (short)(r >> 16);
}

// ---------------- K1: fused L2norm + BN + Linear via bf16 MFMA, fp16 X ------
// Self-contained: converts W->bf16 per block, computes BN scale/shift inline,
// zeroes gcursor (block 0). Output X16 fp16, coalesced via LDS-staged tile.
__global__ __launch_bounds__(256) void k_x(
    const float* __restrict__ H, const float* __restrict__ gamma,
    const float* __restrict__ beta, const float* __restrict__ mean,
    const float* __restrict__ var, const float* __restrict__ W,
    const float* __restrict__ bias, unsigned short* __restrict__ X16,
    int* __restrict__ gcursor)
{
    __shared__ short A_s[64][ASTRIDE];
    __shared__ short B_s[64][ASTRIDE];
    const int t = threadIdx.x;
    const int l = t & 63, wv = t >> 6;
    const int R0 = blockIdx.x * 64;

    if (blockIdx.x == 0 && t < NBUK) gcursor[t] = 0;

    {   // stage B: W^T (fp32, k-major) -> bf16 LDS
        const int n = t >> 2, koff = (t & 3) * 32;
#pragma unroll
        for (int i = 0; i < 16; ++i) {
            const int k = koff + i * 2;
            const unsigned lo = (unsigned short)f2bf(W[k * DOUT + n]);
            const unsigned hi = (unsigned short)f2bf(W[(k + 1) * DOUT + n]);
            *(unsigned*)&B_s[n][k] = lo | (hi << 16);
        }
    }
    {   // stage A: 4 threads per row; BN scale/shift computed inline
        const int rloc = t >> 2, sub = t & 3;
        const int r = R0 + rloc;
        float4 h[8];
        if (r < N_NODES) {
            const float4* hp = (const float4*)(H + (size_t)r * DIN + sub * 32);
#pragma unroll
            for (int i = 0; i < 8; ++i) h[i] = hp[i];
        } else {
#pragma unroll
            for (int i = 0; i < 8; ++i) h[i] = make_float4(0.f, 0.f, 0.f, 0.f);
        }
        float ss = 0.f;
#pragma unroll
        for (int i = 0; i < 8; ++i)
            ss += h[i].x * h[i].x + h[i].y * h[i].y + h[i].z * h[i].z + h[i].w * h[i].w;
        ss += __shfl_xor(ss, 1, 64);
        ss += __shfl_xor(ss, 2, 64);
        const float inv = 1.0f / fmaxf(sqrtf(ss), 1e-12f);

        const float4* gp = (const float4*)(gamma + sub * 32);
        const float4* bp = (const float4*)(beta  + sub * 32);
        const float4* mp = (const float4*)(mean  + sub * 32);
        const float4* vp = (const float4*)(var   + sub * 32);
#pragma unroll
        for (int i = 0; i < 8; ++i) {
            const float4 g4 = gp[i], b4 = bp[i], m4 = mp[i], v4 = vp[i];
            const float s0 = g4.x * rsqrtf(v4.x + 1e-5f);
            const float s1 = g4.y * rsqrtf(v4.y + 1e-5f);
            const float s2 = g4.z * rsqrtf(v4.z + 1e-5f);
            const float s3 = g4.w * rsqrtf(v4.w + 1e-5f);
            const float e0 = h[i].x * inv * s0 + (b4.x - m4.x * s0);
            const float e1 = h[i].y * inv * s1 + (b4.y - m4.y * s1);
            const float e2 = h[i].z * inv * s2 + (b4.z - m4.z * s2);
            const float e3 = h[i].w * inv * s3 + (b4.w - m4.w * s3);
            const unsigned u0 = (unsigned short)f2bf(e0) | ((unsigned)(unsigned short)f2bf(e1) << 16);
            const unsigned u1 = (unsigned short)f2bf(e2) | ((unsigned)(unsigned short)f2bf(e3) << 16);
            *(uint2*)&A_s[rloc][sub * 32 + i * 4] = make_uint2(u0, u1);
        }
    }

    const int ml = l & 15, q = l >> 4;
    f32x4 c0, c1, c2, c3;
    {
        const float b0 = bias[ml],      b1 = bias[16 + ml];
        const float b2 = bias[32 + ml], b3 = bias[48 + ml];
        c0 = f32x4{b0, b0, b0, b0};
        c1 = f32x4{b1, b1, b1, b1};
        c2 = f32x4{b2, b2, b2, b2};
        c3 = f32x4{b3, b3, b3, b3};
    }
    __syncthreads();

#pragma unroll
    for (int k0 = 0; k0 < 4; ++k0) {
        const short8 a  = *(const short8*)&A_s[wv * 16 + ml][k0 * 32 + q * 8];
        const short8 b0 = *(const short8*)&B_s[ml][k0 * 32 + q * 8];
        const short8 b1 = *(const short8*)&B_s[16 + ml][k0 * 32 + q * 8];
        const short8 b2 = *(const short8*)&B_s[32 + ml][k0 * 32 + q * 8];
        const short8 b3 = *(const short8*)&B_s[48 + ml][k0 * 32 + q * 8];
        c0 = __builtin_amdgcn_mfma_f32_16x16x32_bf16(a, b0, c0, 0, 0, 0);
        c1 = __builtin_amdgcn_mfma_f32_16x16x32_bf16(a, b1, c1, 0, 0, 0);
        c2 = __builtin_amdgcn_mfma_f32_16x16x32_bf16(a, b2, c2, 0, 0, 0);
        c3 = __builtin_amdgcn_mfma_f32_16x16x32_bf16(a, b3, c3, 0, 0, 0);
    }

    // epilogue: fp16 tile in LDS (reuse A_s), then coalesced global writes
    __syncthreads();
    unsigned short* otile = (unsigned short*)&A_s[0][0];
#pragma unroll
    for (int i = 0; i < 4; ++i) {
        const int r = wv * 16 + q * 4 + i;
        otile[r * 64 + ml]      = __half_as_ushort(__float2half(c0[i]));
        otile[r * 64 + 16 + ml] = __half_as_ushort(__float2half(c1[i]));
        otile[r * 64 + 32 + ml] = __half_as_ushort(__float2half(c2[i]));
        otile[r * 64 + 48 + ml] = __half_as_ushort(__float2half(c3[i]));
    }
    __syncthreads();
#pragma unroll
    for (int rep = 0; rep < 2; ++rep) {
        const int id = rep * 256 + t;
        const int row = id >> 3;
        const int off = (id & 7) * 8;
        if (R0 + row < N_NODES)
            *(uint4*)(X16 + (size_t)(R0 + row) * DOUT + off) =
                *(const uint4*)&otile[row * 64 + off];
    }
}

// ---------------- K2: pass A — bucket sort into fixed-cap windows -----------
// midVC: fp16(val)<<16 | col   midR: lrow byte
__global__ __launch_bounds__(512) void k_passA(
    const int* __restrict__ rows, const int* __restrict__ cols,
    const float* __restrict__ vals, int* __restrict__ gcursor,
    unsigned* __restrict__ midVC, unsigned char* __restrict__ midR)
{
    __shared__ int lhist[NBUK], lstart[NBUK], lcur[NBUK], gbase[NBUK];
    __shared__ int scn[256];
    __shared__ unsigned lbinVC[CHUNK];
    __shared__ unsigned short lbinBR[CHUNK];
    const int t = threadIdx.x;
    const int e0 = blockIdx.x * CHUNK;
    const int nC = min(CHUNK, E_EDGES - e0);

    if (t < NBUK) lhist[t] = 0;
    __syncthreads();

    unsigned prVC[4];
    unsigned short prBR[4];
#pragma unroll
    for (int k = 0; k < 4; ++k) {
        const int e = e0 + k * 512 + t;
        if (e < E_EDGES) {
            const int r = rows[e];
            const unsigned hv = __half_as_ushort(__float2half(vals[e]));
            prVC[k] = (hv << 16) | (unsigned)cols[e];
            prBR[k] = (unsigned short)r;           // bucket<<8 | lrow == row
            atomicAdd(&lhist[r >> 8], 1);
        } else {
            prBR[k] = 0xFFFFu;                     // bucket 255 >= NBUK
        }
    }
    __syncthreads();

    const int v = (t < NBUK) ? lhist[t] : 0;
    if (t < 256) scn[t] = v;
    __syncthreads();
    for (int o = 1; o < 256; o <<= 1) {
        int u = 0;
        if (t < 256 && t >= o) u = scn[t - o];
        __syncthreads();
        if (t < 256) scn[t] += u;
        __syncthreads();
    }
    if (t < NBUK) {
        const int ex = scn[t] - v;
        lstart[t] = ex;
        lcur[t] = ex;
        gbase[t] = t * BUKCAP + (v ? atomicAdd(&gcursor[t], v) : 0);
    }
    __syncthreads();

#pragma unroll
    for (int k = 0; k < 4; ++k) {
        if (prBR[k] != 0xFFFFu) {
            const int bk = prBR[k] >> 8;
            const int pos = atomicAdd(&lcur[bk], 1);
            lbinVC[pos] = prVC[k];
            lbinBR[pos] = prBR[k];
        }
    }
    __syncthreads();

    for (int i = t; i < nC; i += 512) {
        const unsigned short br = lbinBR[i];
        const int bk = br >> 8;
        const int g = gbase[bk] + (i - lstart[bk]);
        if (g < (bk + 1) * BUKCAP) {               // overflow guard (P ~ 1e-13)
            midVC[g] = lbinVC[i];
            midR[g] = (unsigned char)(br & 255);
        }
    }
}

// ---------------- K3: pass B — exact CSR within each bucket window ----------
__global__ __launch_bounds__(512) void k_passB(
    const int* __restrict__ gcursor, const unsigned* __restrict__ midVC,
    const unsigned char* __restrict__ midR, unsigned* __restrict__ ev,
    int* __restrict__ rowS, int* __restrict__ rowE)
{
    __shared__ int lhist[256], scn[256], lcur[256];
    const int t = threadIdx.x;
    const int b = blockIdx.x;
    const int base = b * BUKCAP;
    const int total = min(gcursor[b], BUKCAP);

    if (t < 256) lhist[t] = 0;
    __syncthreads();
    for (int i = t; i < total; i += 512)
        atomicAdd(&lhist[midR[base + i]], 1);
    __syncthreads();

    const int v = (t < 256) ? lhist[t] : 0;
    if (t < 256) scn[t] = v;
    __syncthreads();
    for (int o = 1; o < 256; o <<= 1) {
        int u = 0;
        if (t < 256 && t >= o) u = scn[t - o];
        __syncthreads();
        if (t < 256) scn[t] += u;
        __syncthreads();
    }
    if (t < 256) {
        const int ex = scn[t] - v;
        lcur[t] = ex;
        const int gr = (b << 8) | t;
        if (gr < N_NODES) { rowS[gr] = base + ex; rowE[gr] = base + ex + v; }
    }
    __syncthreads();

    for (int i = t; i < total; i += 512) {
        const int lr = midR[base + i];
        const int pos = atomicAdd(&lcur[lr], 1);
        ev[base + pos] = midVC[base + i];
    }
}

// ---------------- K4: SpMM + LeakyReLU — wave/row, 4B edges, fp16 X ---------
__global__ __launch_bounds__(256) void k_spmm(
    const int* __restrict__ rowS, const int* __restrict__ rowE,
    const unsigned* __restrict__ ev, const unsigned short* __restrict__ X16,
    float* __restrict__ out)
{
    const int lane = threadIdx.x & 63;
    const int row  = blockIdx.x * 4 + (threadIdx.x >> 6);
    const int s  = rowS[row];
    const int e2 = rowE[row];
    float acc = 0.f;
    for (int c = s; c < e2; c += 64) {
        const int idx = c + lane;
        unsigned p = 0;
        if (idx < e2) p = ev[idx];
        const int cnt = min(e2 - c, 64);
        int j = 0;
        for (; j + 3 < cnt; j += 4) {
            const unsigned u0 = (unsigned)__shfl((int)p, j,     64);
            const unsigned u1 = (unsigned)__shfl((int)p, j + 1, 64);
            const unsigned u2 = (unsigned)__shfl((int)p, j + 2, 64);
            const unsigned u3 = (unsigned)__shfl((int)p, j + 3, 64);
            const float x0 = __half2float(__ushort_as_half(X16[(u0 & 0xFFFFu) * DOUT + lane]));
            const float x1 = __half2float(__ushort_as_half(X16[(u1 & 0xFFFFu) * DOUT + lane]));
            const float x2 = __half2float(__ushort_as_half(X16[(u2 & 0xFFFFu) * DOUT + lane]));
            const float x3 = __half2float(__ushort_as_half(X16[(u3 & 0xFFFFu) * DOUT + lane]));
            const float v0 = __half2float(__ushort_as_half((unsigned short)(u0 >> 16)));
            const float v1 = __half2float(__ushort_as_half((unsigned short)(u1 >> 16)));
            const float v2 = __half2float(__ushort_as_half((unsigned short)(u2 >> 16)));
            const float v3 = __half2float(__ushort_as_half((unsigned short)(u3 >> 16)));
            acc = fmaf(v0, x0, acc);
            acc = fmaf(v1, x1, acc);
            acc = fmaf(v2, x2, acc);
            acc = fmaf(v3, x3, acc);
        }
        for (; j < cnt; ++j) {
            const unsigned u = (unsigned)__shfl((int)p, j, 64);
            const float x = __half2float(__ushort_as_half(X16[(u & 0xFFFFu) * DOUT + lane]));
            const float v = __half2float(__ushort_as_half((unsigned short)(u >> 16)));
            acc = fmaf(v, x, acc);
        }
    }
    out[(size_t)row * DOUT + lane] = (acc >= 0.f) ? acc : 0.01f * acc;
}

extern "C" void kernel_launch(void* const* d_in, const int* in_sizes, int n_in,
                              void* d_out, int out_size, void* d_ws, size_t ws_size,
                              hipStream_t stream)
{
    const float* H     = (const float*)d_in[0];
    const int*   rows  = (const int*)  d_in[1];
    const int*   cols  = (const int*)  d_in[2];
    const float* vals  = (const float*)d_in[3];
    const float* gamma = (const float*)d_in[4];
    const float* beta  = (const float*)d_in[5];
    const float* mean  = (const float*)d_in[6];
    const float* var   = (const float*)d_in[7];
    const float* W     = (const float*)d_in[8];
    const float* bias  = (const float*)d_in[9];
    float* out = (float*)d_out;

    char* ws = (char*)d_ws;
    unsigned short* X16     = (unsigned short*)(ws);             //  6,400,000 B
    int*            gcursor = (int*)          (ws +  6400000);   //        784 B
    unsigned*       midVC   = (unsigned*)     (ws +  6400800);   //  3,612,672 B
    unsigned char*  midR    = (unsigned char*)(ws + 10013472);   //    903,168 B
    unsigned*       ev      = (unsigned*)     (ws + 10916640);   //  3,612,672 B
    int*            rowS    = (int*)          (ws + 14529312);   //    200,704 B
    int*            rowE    = (int*)          (ws + 14730016);   //    200,704 B

    k_x<<<(N_NODES + 63) / 64, 256, 0, stream>>>(H, gamma, beta, mean, var, W,
                                                 bias, X16, gcursor);
    k_passA<<<NBLKA, 512, 0, stream>>>(rows, cols, vals, gcursor, midVC, midR);
    k_passB<<<NBUK, 512, 0, stream>>>(gcursor, midVC, midR, ev, rowS, rowE);
    k_spmm<<<N_NODES / 4, 256, 0, stream>>>(rowS, rowE, ev, X16, out);
}

// Round 9
// 157.110 us; speedup vs baseline: 2.9803x; 1.0176x over previous
//
#include <hip/hip_runtime.h>
#include <hip/hip_fp16.h>

#define N_NODES 50000
#define E_EDGES 800000
#define DIN 128
#define DOUT 64
#define NBUK 196            // bucket = row >> 8
#define BUKCAP 4608         // fixed window capacity (mean ~4082, +8 sigma)
#define CHUNK 2048
#define NBLKA 391           // ceil(E/CHUNK)
#define ASTRIDE 136         // bf16 LDS row stride

typedef short short8 __attribute__((ext_vector_type(8)));
typedef float f32x4 __attribute__((ext_vector_type(4)));

static __device__ __forceinline__ short f2bf(float f)
{
    union { float f; unsigned u; } x{f};
    const unsigned r = x.u + 0x7FFFu + ((x.u >> 16) & 1u);   // RNE
    return (short)(r >> 16);
}

// ---------------- K1: fused L2norm + BN + Linear via bf16 MFMA, fp16 X ------
__global__ __launch_bounds__(256) void k_x(
    const float* __restrict__ H, const float* __restrict__ gamma,
    const float* __restrict__ beta, const float* __restrict__ mean,
    const float* __restrict__ var, const float* __restrict__ W,
    const float* __restrict__ bias, unsigned short* __restrict__ X16,
    int* __restrict__ gcursor)
{
    __shared__ short A_s[64][ASTRIDE];
    __shared__ short B_s[64][ASTRIDE];
    const int t = threadIdx.x;
    const int l = t & 63, wv = t >> 6;
    const int R0 = blockIdx.x * 64;

    if (blockIdx.x == 0 && t < NBUK) gcursor[t] = 0;

    {   // stage B: W^T (fp32, k-major) -> bf16 LDS
        const int n = t >> 2, koff = (t & 3) * 32;
#pragma unroll
        for (int i = 0; i < 16; ++i) {
            const int k = koff + i * 2;
            const unsigned lo = (unsigned short)f2bf(W[k * DOUT + n]);
            const unsigned hi = (unsigned short)f2bf(W[(k + 1) * DOUT + n]);
            *(unsigned*)&B_s[n][k] = lo | (hi << 16);
        }
    }
    {   // stage A: 4 threads per row; BN scale/shift computed inline
        const int rloc = t >> 2, sub = t & 3;
        const int r = R0 + rloc;
        float4 h[8];
        if (r < N_NODES) {
            const float4* hp = (const float4*)(H + (size_t)r * DIN + sub * 32);
#pragma unroll
            for (int i = 0; i < 8; ++i) h[i] = hp[i];
        } else {
#pragma unroll
            for (int i = 0; i < 8; ++i) h[i] = make_float4(0.f, 0.f, 0.f, 0.f);
        }
        float ss = 0.f;
#pragma unroll
        for (int i = 0; i < 8; ++i)
            ss += h[i].x * h[i].x + h[i].y * h[i].y + h[i].z * h[i].z + h[i].w * h[i].w;
        ss += __shfl_xor(ss, 1, 64);
        ss += __shfl_xor(ss, 2, 64);
        const float inv = 1.0f / fmaxf(sqrtf(ss), 1e-12f);

        const float4* gp = (const float4*)(gamma + sub * 32);
        const float4* bp = (const float4*)(beta  + sub * 32);
        const float4* mp = (const float4*)(mean  + sub * 32);
        const float4* vp = (const float4*)(var   + sub * 32);
#pragma unroll
        for (int i = 0; i < 8; ++i) {
            const float4 g4 = gp[i], b4 = bp[i], m4 = mp[i], v4 = vp[i];
            const float s0 = g4.x * rsqrtf(v4.x + 1e-5f);
            const float s1 = g4.y * rsqrtf(v4.y + 1e-5f);
            const float s2 = g4.z * rsqrtf(v4.z + 1e-5f);
            const float s3 = g4.w * rsqrtf(v4.w + 1e-5f);
            const float e0 = h[i].x * inv * s0 + (b4.x - m4.x * s0);
            const float e1 = h[i].y * inv * s1 + (b4.y - m4.y * s1);
            const float e2 = h[i].z * inv * s2 + (b4.z - m4.z * s2);
            const float e3 = h[i].w * inv * s3 + (b4.w - m4.w * s3);
            const unsigned u0 = (unsigned short)f2bf(e0) | ((unsigned)(unsigned short)f2bf(e1) << 16);
            const unsigned u1 = (unsigned short)f2bf(e2) | ((unsigned)(unsigned short)f2bf(e3) << 16);
            *(uint2*)&A_s[rloc][sub * 32 + i * 4] = make_uint2(u0, u1);
        }
    }

    const int ml = l & 15, q = l >> 4;
    f32x4 c0, c1, c2, c3;
    {
        const float b0 = bias[ml],      b1 = bias[16 + ml];
        const float b2 = bias[32 + ml], b3 = bias[48 + ml];
        c0 = f32x4{b0, b0, b0, b0};
        c1 = f32x4{b1, b1, b1, b1};
        c2 = f32x4{b2, b2, b2, b2};
        c3 = f32x4{b3, b3, b3, b3};
    }
    __syncthreads();

#pragma unroll
    for (int k0 = 0; k0 < 4; ++k0) {
        const short8 a  = *(const short8*)&A_s[wv * 16 + ml][k0 * 32 + q * 8];
        const short8 b0 = *(const short8*)&B_s[ml][k0 * 32 + q * 8];
        const short8 b1 = *(const short8*)&B_s[16 + ml][k0 * 32 + q * 8];
        const short8 b2 = *(const short8*)&B_s[32 + ml][k0 * 32 + q * 8];
        const short8 b3 = *(const short8*)&B_s[48 + ml][k0 * 32 + q * 8];
        c0 = __builtin_amdgcn_mfma_f32_16x16x32_bf16(a, b0, c0, 0, 0, 0);
        c1 = __builtin_amdgcn_mfma_f32_16x16x32_bf16(a, b1, c1, 0, 0, 0);
        c2 = __builtin_amdgcn_mfma_f32_16x16x32_bf16(a, b2, c2, 0, 0, 0);
        c3 = __builtin_amdgcn_mfma_f32_16x16x32_bf16(a, b3, c3, 0, 0, 0);
    }

    // epilogue: fp16 tile in LDS (reuse A_s), then coalesced global writes
    __syncthreads();
    unsigned short* otile = (unsigned short*)&A_s[0][0];
#pragma unroll
    for (int i = 0; i < 4; ++i) {
        const int r = wv * 16 + q * 4 + i;
        otile[r * 64 + ml]      = __half_as_ushort(__float2half(c0[i]));
        otile[r * 64 + 16 + ml] = __half_as_ushort(__float2half(c1[i]));
        otile[r * 64 + 32 + ml] = __half_as_ushort(__float2half(c2[i]));
        otile[r * 64 + 48 + ml] = __half_as_ushort(__float2half(c3[i]));
    }
    __syncthreads();
#pragma unroll
    for (int rep = 0; rep < 2; ++rep) {
        const int id = rep * 256 + t;
        const int row = id >> 3;
        const int off = (id & 7) * 8;
        if (R0 + row < N_NODES)
            *(uint4*)(X16 + (size_t)(R0 + row) * DOUT + off) =
                *(const uint4*)&otile[row * 64 + off];
    }
}

// ---------------- K2: pass A — bucket sort into fixed-cap windows -----------
__global__ __launch_bounds__(512) void k_passA(
    const int* __restrict__ rows, const int* __restrict__ cols,
    const float* __restrict__ vals, int* __restrict__ gcursor,
    unsigned* __restrict__ midVC, unsigned char* __restrict__ midR)
{
    __shared__ int lhist[NBUK], lstart[NBUK], lcur[NBUK], gbase[NBUK];
    __shared__ int scn[256];
    __shared__ unsigned lbinVC[CHUNK];
    __shared__ unsigned short lbinBR[CHUNK];
    const int t = threadIdx.x;
    const int e0 = blockIdx.x * CHUNK;
    const int nC = min(CHUNK, E_EDGES - e0);

    if (t < NBUK) lhist[t] = 0;
    __syncthreads();

    unsigned prVC[4];
    unsigned short prBR[4];
#pragma unroll
    for (int k = 0; k < 4; ++k) {
        const int e = e0 + k * 512 + t;
        if (e < E_EDGES) {
            const int r = rows[e];
            const unsigned hv = __half_as_ushort(__float2half(vals[e]));
            prVC[k] = (hv << 16) | (unsigned)cols[e];
            prBR[k] = (unsigned short)r;
            atomicAdd(&lhist[r >> 8], 1);
        } else {
            prBR[k] = 0xFFFFu;
        }
    }
    __syncthreads();

    const int v = (t < NBUK) ? lhist[t] : 0;
    if (t < 256) scn[t] = v;
    __syncthreads();
    for (int o = 1; o < 256; o <<= 1) {
        int u = 0;
        if (t < 256 && t >= o) u = scn[t - o];
        __syncthreads();
        if (t < 256) scn[t] += u;
        __syncthreads();
    }
    if (t < NBUK) {
        const int ex = scn[t] - v;
        lstart[t] = ex;
        lcur[t] = ex;
        gbase[t] = t * BUKCAP + (v ? atomicAdd(&gcursor[t], v) : 0);
    }
    __syncthreads();

#pragma unroll
    for (int k = 0; k < 4; ++k) {
        if (prBR[k] != 0xFFFFu) {
            const int bk = prBR[k] >> 8;
            const int pos = atomicAdd(&lcur[bk], 1);
            lbinVC[pos] = prVC[k];
            lbinBR[pos] = prBR[k];
        }
    }
    __syncthreads();

    for (int i = t; i < nC; i += 512) {
        const unsigned short br = lbinBR[i];
        const int bk = br >> 8;
        const int g = gbase[bk] + (i - lstart[bk]);
        if (g < (bk + 1) * BUKCAP) {
            midVC[g] = lbinVC[i];
            midR[g] = (unsigned char)(br & 255);
        }
    }
}

// ---------------- K3: pass B — exact CSR within each bucket window ----------
__global__ __launch_bounds__(512) void k_passB(
    const int* __restrict__ gcursor, const unsigned* __restrict__ midVC,
    const unsigned char* __restrict__ midR, unsigned* __restrict__ ev,
    int* __restrict__ rowS, int* __restrict__ rowE)
{
    __shared__ int lhist[256], scn[256], lcur[256];
    const int t = threadIdx.x;
    const int b = blockIdx.x;
    const int base = b * BUKCAP;
    const int total = min(gcursor[b], BUKCAP);

    if (t < 256) lhist[t] = 0;
    __syncthreads();
    for (int i = t; i < total; i += 512)
        atomicAdd(&lhist[midR[base + i]], 1);
    __syncthreads();

    const int v = (t < 256) ? lhist[t] : 0;
    if (t < 256) scn[t] = v;
    __syncthreads();
    for (int o = 1; o < 256; o <<= 1) {
        int u = 0;
        if (t < 256 && t >= o) u = scn[t - o];
        __syncthreads();
        if (t < 256) scn[t] += u;
        __syncthreads();
    }
    if (t < 256) {
        const int ex = scn[t] - v;
        lcur[t] = ex;
        const int gr = (b << 8) | t;
        if (gr < N_NODES) { rowS[gr] = base + ex; rowE[gr] = base + ex + v; }
    }
    __syncthreads();

    for (int i = t; i < total; i += 512) {
        const int lr = midR[base + i];
        const int pos = atomicAdd(&lcur[lr], 1);
        ev[base + pos] = midVC[base + i];
    }
}

// ---------------- K4: SpMM + LeakyReLU — half-wave per edge, fp16 X ---------
// Wave per row; each round loads 64 edges coalesced, then the two half-waves
// process 2 edges per step (lane covers 2 cols via packed half2 gather).
// Tail edges self-handle: p=0 -> val=0, col=0 (valid address, adds 0).
__global__ __launch_bounds__(256) void k_spmm(
    const int* __restrict__ rowS, const int* __restrict__ rowE,
    const unsigned* __restrict__ ev, const unsigned short* __restrict__ X16,
    float* __restrict__ out)
{
    const int lane = threadIdx.x & 63;
    const int hl   = lane & 31;          // column-pair index (cols 2hl, 2hl+1)
    const int h    = lane >> 5;          // half-wave id
    const int row  = blockIdx.x * 4 + (threadIdx.x >> 6);
    const int s  = rowS[row];
    const int e2 = rowE[row];
    float ax = 0.f, ay = 0.f;
    for (int c = s; c < e2; c += 64) {
        const int idx = c + lane;
        unsigned p = 0;
        if (idx < e2) p = ev[idx];
        const int cnt  = min(e2 - c, 64);
        const int jmax = (cnt + 1) >> 1;
        int j = 0;
        for (; j + 1 < jmax; j += 2) {
            const unsigned u0 = (unsigned)__shfl((int)p, 2 * j + h,     64);
            const unsigned u1 = (unsigned)__shfl((int)p, 2 * j + 2 + h, 64);
            const unsigned x0 = *(const unsigned*)(X16 + (u0 & 0xFFFFu) * DOUT + 2 * hl);
            const unsigned x1 = *(const unsigned*)(X16 + (u1 & 0xFFFFu) * DOUT + 2 * hl);
            const float v0 = __half2float(__ushort_as_half((unsigned short)(u0 >> 16)));
            const float v1 = __half2float(__ushort_as_half((unsigned short)(u1 >> 16)));
            const float2 f0 = __half22float2(*(const __half2*)&x0);
            const float2 f1 = __half22float2(*(const __half2*)&x1);
            ax = fmaf(v0, f0.x, ax); ay = fmaf(v0, f0.y, ay);
            ax = fmaf(v1, f1.x, ax); ay = fmaf(v1, f1.y, ay);
        }
        for (; j < jmax; ++j) {
            const unsigned u = (unsigned)__shfl((int)p, 2 * j + h, 64);
            const unsigned x = *(const unsigned*)(X16 + (u & 0xFFFFu) * DOUT + 2 * hl);
            const float v = __half2float(__ushort_as_half((unsigned short)(u >> 16)));
            const float2 f = __half22float2(*(const __half2*)&x);
            ax = fmaf(v, f.x, ax); ay = fmaf(v, f.y, ay);
        }
    }
    // combine the two half-waves (same column pair in lanes L and L+32)
    ax += __shfl_xor(ax, 32, 64);
    ay += __shfl_xor(ay, 32, 64);
    if (h == 0) {
        float2 r;
        r.x = (ax >= 0.f) ? ax : 0.01f * ax;
        r.y = (ay >= 0.f) ? ay : 0.01f * ay;
        *(float2*)(out + (size_t)row * DOUT + 2 * hl) = r;
    }
}

extern "C" void kernel_launch(void* const* d_in, const int* in_sizes, int n_in,
                              void* d_out, int out_size, void* d_ws, size_t ws_size,
                              hipStream_t stream)
{
    const float* H     = (const float*)d_in[0];
    const int*   rows  = (const int*)  d_in[1];
    const int*   cols  = (const int*)  d_in[2];
    const float* vals  = (const float*)d_in[3];
    const float* gamma = (const float*)d_in[4];
    const float* beta  = (const float*)d_in[5];
    const float* mean  = (const float*)d_in[6];
    const float* var   = (const float*)d_in[7];
    const float* W     = (const float*)d_in[8];
    const float* bias  = (const float*)d_in[9];
    float* out = (float*)d_out;

    char* ws = (char*)d_ws;
    unsigned short* X16     = (unsigned short*)(ws);             //  6,400,000 B
    int*            gcursor = (int*)          (ws +  6400000);   //        784 B
    unsigned*       midVC   = (unsigned*)     (ws +  6400800);   //  3,612,672 B
    unsigned char*  midR    = (unsigned char*)(ws + 10013472);   //    903,168 B
    unsigned*       ev      = (unsigned*)     (ws + 10916640);   //  3,612,672 B
    int*            rowS    = (int*)          (ws + 14529312);   //    200,704 B
    int*            rowE    = (int*)          (ws + 14730016);   //    200,704 B

    k_x<<<(N_NODES + 63) / 64, 256, 0, stream>>>(H, gamma, beta, mean, var, W,
                                                 bias, X16, gcursor);
    k_passA<<<NBLKA, 512, 0, stream>>>(rows, cols, vals, gcursor, midVC, midR);
    k_passB<<<NBUK, 512, 0, stream>>>(gcursor, midVC, midR, ev, rowS, rowE);
    k_spmm<<<N_NODES / 4, 256, 0, stream>>>(rowS, rowE, ev, X16, out);
}